// Round 8
// baseline (262.207 us; speedup 1.0000x reference)
//
#include <hip/hip_runtime.h>
#include <hip/hip_bf16.h>

#define B_ROWS 131072
#define H 128

typedef __bf16 bf16x8 __attribute__((ext_vector_type(8)));
typedef float f32x4 __attribute__((ext_vector_type(4)));

#define LOG2E 1.4426950408889634f

__device__ __forceinline__ float fast_sigmoid(float x) {
    return __builtin_amdgcn_rcpf(1.0f + __builtin_amdgcn_exp2f(-LOG2E * x));
}
__device__ __forceinline__ float fast_tanh(float x) {
    return 1.0f - 2.0f * __builtin_amdgcn_rcpf(1.0f + __builtin_amdgcn_exp2f(2.0f * LOG2E * x));
}

struct WPtrs {
    const float* wx[4];
    const float* wh[4];
    const float* bx[4];
    const float* bh[4];
};

// Wcat[n][k]: n = gate*128 + hidden_unit, k in [0,256) = [X-k | h-k]. bsum[n] = bx+bh.
__global__ __launch_bounds__(256) void prep_weights(WPtrs p, __bf16* __restrict__ wcat,
                                                    float* __restrict__ bsum) {
    int n = blockIdx.x;      // 0..511
    int k = threadIdx.x;     // 0..255
    int g = n >> 7, r = n & 127;
    float v = (k < H) ? p.wx[g][r * H + k] : p.wh[g][r * H + (k - H)];
    wcat[n * 256 + k] = (__bf16)v;
    if (k == 0) bsum[n] = p.bx[g][r] + p.bh[g][r];
}

// Barrier-free, LDS-free design: 4096 blocks x 512 thr; each wave independently
// computes a 32-row x 16-unit x 4-gate tile. A-fragments load straight from global
// (wave covers 16 rows x 128B = full lines, L1-shared by the block's 8 waves);
// B streams from the L2-resident 256KB Wcat; all loads of a wave are in flight
// together (no barrier drains, no vmcnt FIFO cross-phase serialization).
__global__ __launch_bounds__(512) void lstm_fused(
    const float* __restrict__ X, const float* __restrict__ Hp, const float* __restrict__ Cp,
    const __bf16* __restrict__ Wcat, const float* __restrict__ Bsum,
    float* __restrict__ out)
{
    const int t = threadIdx.x;
    const int lane = t & 63;
    const int cg = t >> 6;                   // wave 0..7 -> units [cg*16, cg*16+16)
    const int l16 = lane & 15;
    const int kg = lane >> 4;                // 0..3
    const long r0 = (long)blockIdx.x * 32;
    const long c_off = (long)B_ROWS * H;

    const int j = cg * 16 + l16;             // this lane's hidden unit (all 4 gates)
    const __bf16* wbase = Wcat + (long)j * 256 + kg * 8;

    float bias[4];
#pragma unroll
    for (int g = 0; g < 4; ++g) bias[g] = Bsum[g * H + j];

    f32x4 acc[4][2] = {};                    // [gate][row-tile]

#pragma unroll
    for (int kc = 0; kc < 8; ++kc) {
        // B fragments: unit j, k = kc*32 + kg*8 .. +8 (L2-resident)
        bf16x8 b[4];
#pragma unroll
        for (int g = 0; g < 4; ++g)
            b[g] = *(const bf16x8*)(wbase + g * (128 * 256) + kc * 32);

        // A fragments straight from global f32, converted to bf16 in-register.
        // k<128 -> X, k>=128 -> Hp.
        bf16x8 a[2];
#pragma unroll
        for (int rt = 0; rt < 2; ++rt) {
            long row = r0 + rt * 16 + l16;
            const float* ap = (kc < 4 ? X + row * H + kc * 32
                                      : Hp + row * H + (kc - 4) * 32) + kg * 8;
            float4 lo = *(const float4*)ap;
            float4 hi = *(const float4*)(ap + 4);
            union { __bf16 e[8]; bf16x8 v; } u;
            u.e[0] = (__bf16)lo.x; u.e[1] = (__bf16)lo.y;
            u.e[2] = (__bf16)lo.z; u.e[3] = (__bf16)lo.w;
            u.e[4] = (__bf16)hi.x; u.e[5] = (__bf16)hi.y;
            u.e[6] = (__bf16)hi.z; u.e[7] = (__bf16)hi.w;
            a[rt] = u.v;
        }

#pragma unroll
        for (int g = 0; g < 4; ++g) {
            acc[g][0] = __builtin_amdgcn_mfma_f32_16x16x32_bf16(a[0], b[g], acc[g][0], 0, 0, 0);
            acc[g][1] = __builtin_amdgcn_mfma_f32_16x16x32_bf16(a[1], b[g], acc[g][1], 0, 0, 0);
        }
    }

    // c_prev loads (issued after the K-loop load stream; latency overlaps MFMA drain)
    float cpv[8];
#pragma unroll
    for (int rt = 0; rt < 2; ++rt)
#pragma unroll
        for (int r = 0; r < 4; ++r)
            cpv[rt * 4 + r] = Cp[(r0 + rt * 16 + kg * 4 + r) * H + j];

    // epilogue: gates lane-local (C/D layout row=(lane>>4)*4+reg, col=lane&15)
#pragma unroll
    for (int rt = 0; rt < 2; ++rt) {
#pragma unroll
        for (int r = 0; r < 4; ++r) {
            long row = r0 + rt * 16 + kg * 4 + r;
            float f  = acc[0][rt][r] + bias[0];
            float ii = acc[1][rt][r] + bias[1];
            float cl = acc[2][rt][r] + bias[2];
            float oo = acc[3][rt][r] + bias[3];
            float ft = fast_sigmoid(f);
            float it = fast_sigmoid(ii);
            float cc = fast_tanh(cl);
            float ot = fast_sigmoid(oo);
            float ct = ft * cpv[rt * 4 + r] + it * cc;
            float ht = ot * fast_tanh(ct);
            out[row * H + j] = ht;
            out[c_off + row * H + j] = ct;
        }
    }
}

extern "C" void kernel_launch(void* const* d_in, const int* in_sizes, int n_in,
                              void* d_out, int out_size, void* d_ws, size_t ws_size,
                              hipStream_t stream) {
    const float* X  = (const float*)d_in[0];
    const float* Hp = (const float*)d_in[1];
    const float* Cp = (const float*)d_in[2];
    WPtrs p;
    p.wx[0] = (const float*)d_in[3];  p.bx[0] = (const float*)d_in[4];
    p.wh[0] = (const float*)d_in[5];  p.bh[0] = (const float*)d_in[6];
    p.wx[1] = (const float*)d_in[7];  p.bx[1] = (const float*)d_in[8];
    p.wh[1] = (const float*)d_in[9];  p.bh[1] = (const float*)d_in[10];
    p.wx[2] = (const float*)d_in[11]; p.bx[2] = (const float*)d_in[12];
    p.wh[2] = (const float*)d_in[13]; p.bh[2] = (const float*)d_in[14];
    p.wx[3] = (const float*)d_in[15]; p.bx[3] = (const float*)d_in[16];
    p.wh[3] = (const float*)d_in[17]; p.bh[3] = (const float*)d_in[18];

    __bf16* wcat = (__bf16*)d_ws;
    float*  bsum = (float*)((char*)d_ws + 512 * 256 * 2);

    prep_weights<<<512, 256, 0, stream>>>(p, wcat, bsum);
    lstm_fused<<<B_ROWS / 32, 512, 0, stream>>>(X, Hp, Cp, wcat, bsum, (float*)d_out);
}

// Round 9
// 172.131 us; speedup vs baseline: 1.5233x; 1.5233x over previous
//
#include <hip/hip_runtime.h>
#include <hip/hip_bf16.h>

#define B_ROWS 131072
#define H 128
#define NSLAB 8           // slabs per block
#define SLAB_ROWS 64      // rows per block-slab (2 rg x 32)

typedef __bf16 bf16x8 __attribute__((ext_vector_type(8)));
typedef float f32x4 __attribute__((ext_vector_type(4)));

#define LOG2E 1.4426950408889634f

__device__ __forceinline__ float fast_sigmoid(float x) {
    return __builtin_amdgcn_rcpf(1.0f + __builtin_amdgcn_exp2f(-LOG2E * x));
}
__device__ __forceinline__ float fast_tanh(float x) {
    return 1.0f - 2.0f * __builtin_amdgcn_rcpf(1.0f + __builtin_amdgcn_exp2f(2.0f * LOG2E * x));
}

struct WPtrs {
    const float* wx[4];
    const float* wh[4];
    const float* bx[4];
    const float* bh[4];
};

// Wcat[n][k]: n = gate*128 + hidden_unit, k in [0,256) = [X-k | h-k]. bsum[n] = bx+bh.
__global__ __launch_bounds__(256) void prep_weights(WPtrs p, __bf16* __restrict__ wcat,
                                                    float* __restrict__ bsum) {
    int n = blockIdx.x;      // 0..511
    int k = threadIdx.x;     // 0..255
    int g = n >> 7, r = n & 127;
    float v = (k < H) ? p.wx[g][r * H + k] : p.wh[g][r * H + (k - H)];
    wcat[n * 256 + k] = (__bf16)v;
    if (k == 0) bsum[n] = p.bx[g][r] + p.bh[g][r];
}

__device__ __forceinline__ void loadA(const float* __restrict__ X, const float* __restrict__ Hp,
                                      long srow, int rowoff, int kc, int kg, int l16,
                                      float4 dst[4]) {
    const float* src = (kc < 4) ? X : Hp;
    const int col = (kc & 3) * 32 + kg * 8;
#pragma unroll
    for (int rt = 0; rt < 2; ++rt) {
        const float* p = src + (srow + rowoff + rt * 16 + l16) * (long)H + col;
        dst[rt * 2 + 0] = *(const float4*)p;
        dst[rt * 2 + 1] = *(const float4*)(p + 4);
    }
}

// Weight-in-LDS, barrier-free main loop. Block = 512 thr (8 waves = 2 rg x 4 ug),
// owns 64 hidden units x 4 gates; W-slice 128 KB LDS loaded once (ONE barrier).
// Wave = 32 rows x 16 units, iterates 8 slabs with a 2-stage A prefetch pipeline.
// B-reads are ds_read (lgkmcnt) -> A/cp HBM loads (vmcnt) are never force-drained
// by the MFMA loop: the vmcnt FIFO entanglement that capped R3/R7 is gone.
// (512,1): cap 256 VGPR -> no 44-VGPR starvation (R8), no 128-pin spill (R5/R7).
__global__ __launch_bounds__(512, 1) void lstm_fused(
    const float* __restrict__ X, const float* __restrict__ Hp, const float* __restrict__ Cp,
    const __bf16* __restrict__ Wcat, const float* __restrict__ Bsum,
    float* __restrict__ out)
{
    __shared__ char wlds[256 * 512];   // 128 KB: row r' = g*64+u  <->  Wcat row g*128+ub*64+u

    const int t = threadIdx.x;
    const int lane = t & 63;
    const int wv = t >> 6;
    const int rg = wv >> 2;            // 0..1 : rows rg*32..+32 within slab
    const int ug = wv & 3;             // 0..3 : units ug*16..+16 within the 64
    const int l16 = lane & 15;
    const int kg = lane >> 4;          // 0..3
    const int ub = blockIdx.x & 1;     // unit half (paired blocks share row-slabs via L3)
    const int rs0 = blockIdx.x >> 1;   // 0..255
    const long c_off = (long)B_ROWS * H;
    const int j = ub * 64 + ug * 16 + l16;   // this lane's hidden unit (all 4 gates)
    const int rowoff = rg * 32;

    // ---- W slice -> LDS (once), XOR-swizzled ----
    {
        int r = t >> 1;                // 0..255
        int hh = t & 1;                // 256B half
        int g = r >> 6, u = r & 63;
        const char* src = (const char*)(Wcat + ((long)(g * 128 + ub * 64 + u)) * 256) + hh * 256;
        char* dst = wlds + r * 512;
        int swz = (r & 7) << 4;
#pragma unroll
        for (int i = 0; i < 16; ++i)
            *(float4*)(dst + ((hh * 256 + i * 16) ^ swz)) = *(const float4*)(src + i * 16);
    }
    float bias[4];
#pragma unroll
    for (int g = 0; g < 4; ++g) bias[g] = Bsum[g * H + j];
    __syncthreads();                   // the only barrier

    float4 A0[4], A1[4];
    float cpv[8], cpn[8];

    const long srow0 = (long)rs0 * SLAB_ROWS;
    loadA(X, Hp, srow0, rowoff, 0, kg, l16, A0);
#pragma unroll
    for (int rt = 0; rt < 2; ++rt)
#pragma unroll
        for (int r = 0; r < 4; ++r)
            cpv[rt * 4 + r] = Cp[(srow0 + rowoff + rt * 16 + kg * 4 + r) * (long)H + j];

    for (int s = 0; s < NSLAB; ++s) {
        const long srow = ((long)rs0 + (long)s * 256) * SLAB_ROWS;
        const long nraw = ((long)rs0 + (long)(s + 1) * 256) * SLAB_ROWS;
        const long nsrow = (nraw < B_ROWS) ? nraw : 0;   // clamp: harmless dummy prefetch

        f32x4 acc[4][2] = {};          // [gate][rt]
#pragma unroll
        for (int kc = 0; kc < 8; ++kc) {
            float4* cur = (kc & 1) ? A1 : A0;
            float4* nxt = (kc & 1) ? A0 : A1;
            if (kc < 7) loadA(X, Hp, srow, rowoff, kc + 1, kg, l16, nxt);
            else        loadA(X, Hp, nsrow, rowoff, 0, kg, l16, nxt);
            if (kc == 3) {             // next-slab cp prefetch: ~5 kc + epilogue of cover
#pragma unroll
                for (int rt = 0; rt < 2; ++rt)
#pragma unroll
                    for (int r = 0; r < 4; ++r)
                        cpn[rt * 4 + r] = Cp[(nsrow + rowoff + rt * 16 + kg * 4 + r) * (long)H + j];
            }

            bf16x8 b[4];
#pragma unroll
            for (int g = 0; g < 4; ++g) {
                int rr = g * 64 + ug * 16 + l16;
                int off = rr * 512 + ((kc * 64 + kg * 16) ^ ((rr & 7) << 4));
                b[g] = *(const bf16x8*)(wlds + off);
            }

            bf16x8 a[2];
#pragma unroll
            for (int rt = 0; rt < 2; ++rt) {
                union { __bf16 e[8]; bf16x8 v; } u;
                float4 lo = cur[rt * 2], hi = cur[rt * 2 + 1];
                u.e[0] = (__bf16)lo.x; u.e[1] = (__bf16)lo.y;
                u.e[2] = (__bf16)lo.z; u.e[3] = (__bf16)lo.w;
                u.e[4] = (__bf16)hi.x; u.e[5] = (__bf16)hi.y;
                u.e[6] = (__bf16)hi.z; u.e[7] = (__bf16)hi.w;
                a[rt] = u.v;
            }

#pragma unroll
            for (int g = 0; g < 4; ++g) {
                acc[g][0] = __builtin_amdgcn_mfma_f32_16x16x32_bf16(a[0], b[g], acc[g][0], 0, 0, 0);
                acc[g][1] = __builtin_amdgcn_mfma_f32_16x16x32_bf16(a[1], b[g], acc[g][1], 0, 0, 0);
            }
        }

        // ---- epilogue: gates lane-local (C/D row=(lane>>4)*4+reg, col=lane&15) ----
#pragma unroll
        for (int rt = 0; rt < 2; ++rt) {
#pragma unroll
            for (int r = 0; r < 4; ++r) {
                long row = srow + rowoff + rt * 16 + kg * 4 + r;
                float f  = acc[0][rt][r] + bias[0];
                float ii = acc[1][rt][r] + bias[1];
                float cl = acc[2][rt][r] + bias[2];
                float oo = acc[3][rt][r] + bias[3];
                float ft = fast_sigmoid(f);
                float it = fast_sigmoid(ii);
                float cc = fast_tanh(cl);
                float ot = fast_sigmoid(oo);
                float ct = ft * cpv[rt * 4 + r] + it * cc;
                float ht = ot * fast_tanh(ct);
                out[row * H + j] = ht;
                out[c_off + row * H + j] = ct;
            }
        }
#pragma unroll
        for (int q = 0; q < 8; ++q) cpv[q] = cpn[q];
    }
}

extern "C" void kernel_launch(void* const* d_in, const int* in_sizes, int n_in,
                              void* d_out, int out_size, void* d_ws, size_t ws_size,
                              hipStream_t stream) {
    const float* X  = (const float*)d_in[0];
    const float* Hp = (const float*)d_in[1];
    const float* Cp = (const float*)d_in[2];
    WPtrs p;
    p.wx[0] = (const float*)d_in[3];  p.bx[0] = (const float*)d_in[4];
    p.wh[0] = (const float*)d_in[5];  p.bh[0] = (const float*)d_in[6];
    p.wx[1] = (const float*)d_in[7];  p.bx[1] = (const float*)d_in[8];
    p.wh[1] = (const float*)d_in[9];  p.bh[1] = (const float*)d_in[10];
    p.wx[2] = (const float*)d_in[11]; p.bx[2] = (const float*)d_in[12];
    p.wh[2] = (const float*)d_in[13]; p.bh[2] = (const float*)d_in[14];
    p.wx[3] = (const float*)d_in[15]; p.bx[3] = (const float*)d_in[16];
    p.wh[3] = (const float*)d_in[17]; p.bh[3] = (const float*)d_in[18];

    __bf16* wcat = (__bf16*)d_ws;
    float*  bsum = (float*)((char*)d_ws + 512 * 256 * 2);

    prep_weights<<<512, 256, 0, stream>>>(p, wcat, bsum);
    lstm_fused<<<512, 512, 0, stream>>>(X, Hp, Cp, wcat, bsum, (float*)d_out);
}

// Round 10
// 115.899 us; speedup vs baseline: 2.2624x; 1.4852x over previous
//
#include <hip/hip_runtime.h>
#include <hip/hip_bf16.h>

#define B_ROWS 131072
#define H 128
#define SLAB 16
#define NSLAB 16                 // 256 rows per block
#define NBLK 1024                // 512 row-groups x 2 unit-halves

typedef __bf16 bf16x8 __attribute__((ext_vector_type(8)));
typedef float f32x4 __attribute__((ext_vector_type(4)));

#define LOG2E 1.4426950408889634f
#define GLP(p) ((const __attribute__((address_space(1))) void*)(p))
#define LLP(p) ((__attribute__((address_space(3))) void*)(p))

__device__ __forceinline__ float fast_sigmoid(float v) {
    return __builtin_amdgcn_rcpf(1.0f + __builtin_amdgcn_exp2f(-LOG2E * v));
}
__device__ __forceinline__ float fast_tanh(float v) {
    return 1.0f - 2.0f * __builtin_amdgcn_rcpf(1.0f + __builtin_amdgcn_exp2f(2.0f * LOG2E * v));
}

struct WPtrs {
    const float* wx[4];
    const float* wh[4];
    const float* bx[4];
    const float* bh[4];
};

// Wcat[n][k]: n = gate*128 + unit, k in [0,256) = [X-k | h-k]. bsum[n] = bx+bh.
__global__ __launch_bounds__(256) void prep_weights(WPtrs p, __bf16* __restrict__ wcat,
                                                    float* __restrict__ bsum) {
    int n = blockIdx.x;
    int k = threadIdx.x;
    int g = n >> 7, r = n & 127;
    float v = (k < H) ? p.wx[g][r * H + k] : p.wh[g][r * H + (k - H)];
    wcat[n * 256 + k] = (__bf16)v;
    if (k == 0) bsum[n] = p.bx[g][r] + p.bh[g][r];
}

// 256 thr / 4 waves; block = 64 units x 4 gates x 256-row strip (16 slabs of 16).
// Weights LDS-resident (128 KB, DMA'd once) -> in-loop B reads are lgkm-only.
// A: global->reg (2 slabs ahead) -> bf16 swizzled LDS (dbuf 2x8KB). One raw
// lgkmcnt(0)+s_barrier per slab; vmcnt is managed exactly by the compiler's
// register-dependency tracking (no __syncthreads -> no vmcnt(0) drains).
__global__ __launch_bounds__(256, 1) void lstm_fused(
    const float* __restrict__ X, const float* __restrict__ Hp, const float* __restrict__ Cp,
    const __bf16* __restrict__ Wcat, const float* __restrict__ Bsum,
    float* __restrict__ out)
{
    __shared__ char wlds[256 * 512];        // 128 KB: w-row = g*64 + u_local, 512 B each
    __shared__ char abuf[2][SLAB * 512];    // 2 x 8 KB bf16 [X|h] slab, XOR-swizzled

    const int t = threadIdx.x;
    const int lane = t & 63;
    const int wv = t >> 6;                  // 0..3: unit group
    const int l16 = lane & 15;
    const int kg = lane >> 4;               // 0..3
    const int x = l16 & 7;

    // pair blocks (B, B+8) -> same rows, unit halves, SAME XCD (blockIdx%8)
    const int Bk = blockIdx.x;
    const int ub = (Bk >> 3) & 1;
    const int rb = (Bk & 7) | ((Bk >> 4) << 3);   // 0..511
    const long base = (long)rb * (SLAB * NSLAB);
    const long c_off = (long)B_ROWS * H;
    const int j = ub * 64 + wv * 16 + l16;  // this lane's unit (all 4 gates)

    // ---- weights -> LDS via DMA, once (32 insts/wave, 2 w-rows each) ----
#pragma unroll
    for (int i = 0; i < 32; ++i) {
        int r2 = wv * 64 + 2 * i;
        int rp = r2 + (lane >> 5);          // this lane's w-row
        int g = rp >> 6, u = rp & 63;
        const __bf16* src = Wcat + ((long)(g * 128 + ub * 64 + u)) * 256
                          + (((lane & 31) ^ (rp & 7)) << 3);
        __builtin_amdgcn_global_load_lds(GLP(src), LLP(wlds + r2 * 512), 16, 0, 0);
    }

    float bias[4];
#pragma unroll
    for (int g = 0; g < 4; ++g) bias[g] = Bsum[g * H + j];

    const int s_g8 = t & 31;                // 8-float group within a row
    const int s_r = t >> 5;                 // base row (q adds 8)

    auto stage_load = [&](float4* L, long srow) {
#pragma unroll
        for (int q = 0; q < 2; ++q) {
            int row = q * 8 + s_r;
            const float* sp = (s_g8 < 16) ? (X + (srow + row) * H + s_g8 * 8)
                                          : (Hp + (srow + row) * H + (s_g8 - 16) * 8);
            L[q * 2]     = *(const float4*)sp;
            L[q * 2 + 1] = *(const float4*)(sp + 4);
        }
    };
    auto write_slab = [&](char* buf, const float4* W) {
#pragma unroll
        for (int q = 0; q < 2; ++q) {
            int row = q * 8 + s_r;
            union { __bf16 e[8]; bf16x8 v; } u;
            float4 lo = W[q * 2], hi = W[q * 2 + 1];
            u.e[0] = (__bf16)lo.x; u.e[1] = (__bf16)lo.y;
            u.e[2] = (__bf16)lo.z; u.e[3] = (__bf16)lo.w;
            u.e[4] = (__bf16)hi.x; u.e[5] = (__bf16)hi.y;
            u.e[6] = (__bf16)hi.z; u.e[7] = (__bf16)hi.w;
            *(bf16x8*)(buf + row * 512 + ((s_g8 ^ (row & 7)) << 4)) = u.v;
        }
    };
    auto load_cp = [&](float* c, long srow) {
#pragma unroll
        for (int r = 0; r < 4; ++r) c[r] = Cp[(srow + kg * 4 + r) * H + j];
    };

    float4 RA[4], RB[4];
    float cpv[4], cpn[4];

    // prologue: slab0 -> buf0 (its auto vmcnt wait also drains the weight DMA)
    stage_load(RB, base);                   // slab 0
    load_cp(cpv, base);
    stage_load(RA, base + SLAB);            // slab 1
    write_slab(abuf[0], RB);

#define BODY(S, W, L, BW, BC) {                                                   \
    const long srow = base + (long)(S) * SLAB;                                    \
    const long pn1 = ((S) + 1 < NSLAB) ? (S) + 1 : NSLAB - 1;                     \
    const long pn2 = ((S) + 2 < NSLAB) ? (S) + 2 : NSLAB - 1;                     \
    stage_load(L, base + pn2 * SLAB);                                             \
    load_cp(cpn, base + pn1 * SLAB);                                              \
    asm volatile("s_waitcnt lgkmcnt(0)\n\ts_barrier" ::: "memory");               \
    write_slab(abuf[BW], W);                                                      \
    const char* ac = abuf[BC];                                                    \
    f32x4 acc[4] = {};                                                            \
    _Pragma("unroll")                                                             \
    for (int kc = 0; kc < 8; ++kc) {                                              \
        int grp = (((kc * 4) + kg) ^ x) << 4;                                     \
        bf16x8 av = *(const bf16x8*)(ac + l16 * 512 + grp);                       \
        _Pragma("unroll")                                                         \
        for (int g = 0; g < 4; ++g) {                                             \
            bf16x8 bv = *(const bf16x8*)(wlds + (g * 64 + wv * 16 + l16) * 512 + grp); \
            acc[g] = __builtin_amdgcn_mfma_f32_16x16x32_bf16(av, bv, acc[g], 0, 0, 0); \
        }                                                                         \
    }                                                                             \
    _Pragma("unroll")                                                             \
    for (int r = 0; r < 4; ++r) {                                                 \
        long row = srow + kg * 4 + r;                                             \
        float fg = acc[0][r] + bias[0];                                           \
        float ig = acc[1][r] + bias[1];                                           \
        float cg = acc[2][r] + bias[2];                                           \
        float og = acc[3][r] + bias[3];                                           \
        float ft = fast_sigmoid(fg);                                              \
        float it = fast_sigmoid(ig);                                              \
        float cc = fast_tanh(cg);                                                 \
        float ot = fast_sigmoid(og);                                              \
        float ct = ft * cpv[r] + it * cc;                                         \
        float ht = ot * fast_tanh(ct);                                            \
        out[row * H + j] = ht;                                                    \
        out[c_off + row * H + j] = ct;                                            \
    }                                                                             \
    _Pragma("unroll")                                                             \
    for (int r = 0; r < 4; ++r) cpv[r] = cpn[r];                                  \
}

    for (int sp = 0; sp < NSLAB / 2; ++sp) {
        BODY(2 * sp,     RA, RB, 1, 0);     // write buf1 (slab 2sp+1), compute buf0
        BODY(2 * sp + 1, RB, RA, 0, 1);     // write buf0 (slab 2sp+2), compute buf1
    }
#undef BODY
}

extern "C" void kernel_launch(void* const* d_in, const int* in_sizes, int n_in,
                              void* d_out, int out_size, void* d_ws, size_t ws_size,
                              hipStream_t stream) {
    const float* X  = (const float*)d_in[0];
    const float* Hp = (const float*)d_in[1];
    const float* Cp = (const float*)d_in[2];
    WPtrs p;
    p.wx[0] = (const float*)d_in[3];  p.bx[0] = (const float*)d_in[4];
    p.wh[0] = (const float*)d_in[5];  p.bh[0] = (const float*)d_in[6];
    p.wx[1] = (const float*)d_in[7];  p.bx[1] = (const float*)d_in[8];
    p.wh[1] = (const float*)d_in[9];  p.bh[1] = (const float*)d_in[10];
    p.wx[2] = (const float*)d_in[11]; p.bx[2] = (const float*)d_in[12];
    p.wh[2] = (const float*)d_in[13]; p.bh[2] = (const float*)d_in[14];
    p.wx[3] = (const float*)d_in[15]; p.bx[3] = (const float*)d_in[16];
    p.wh[3] = (const float*)d_in[17]; p.bh[3] = (const float*)d_in[18];

    __bf16* wcat = (__bf16*)d_ws;
    float*  bsum = (float*)((char*)d_ws + 512 * 256 * 2);

    prep_weights<<<512, 256, 0, stream>>>(p, wcat, bsum);
    lstm_fused<<<NBLK, 256, 0, stream>>>(X, Hp, Cp, wcat, bsum, (float*)d_out);
}

// Round 11
// 88.132 us; speedup vs baseline: 2.9752x; 1.3151x over previous
//
#include <hip/hip_runtime.h>
#include <hip/hip_bf16.h>

#define B_ROWS 131072
#define H 128
#define SLAB 16
#define NSLAB 16                 // 256 rows per block strip
#define NBLK 512

typedef __bf16 bf16x8 __attribute__((ext_vector_type(8)));
typedef float f32x4 __attribute__((ext_vector_type(4)));

#define LOG2E 1.4426950408889634f

__device__ __forceinline__ float fast_sigmoid(float v) {
    return __builtin_amdgcn_rcpf(1.0f + __builtin_amdgcn_exp2f(-LOG2E * v));
}
__device__ __forceinline__ float fast_tanh(float v) {
    return 1.0f - 2.0f * __builtin_amdgcn_rcpf(1.0f + __builtin_amdgcn_exp2f(2.0f * LOG2E * v));
}

struct WPtrs {
    const float* wx[4];
    const float* wh[4];
    const float* bx[4];
    const float* bh[4];
};

// Wcat[n][k]: n = gate*128 + unit, k in [0,256) = [X-k | h-k]. bsum[n] = bx+bh.
__global__ __launch_bounds__(256) void prep_weights(WPtrs p, __bf16* __restrict__ wcat,
                                                    float* __restrict__ bsum) {
    int n = blockIdx.x;
    int k = threadIdx.x;
    int g = n >> 7, r = n & 127;
    float v = (k < H) ? p.wx[g][r * H + k] : p.wh[g][r * H + (k - H)];
    wcat[n * 256 + k] = (__bf16)v;
    if (k == 0) bsum[n] = p.bx[g][r] + p.bh[g][r];
}

// 512 thr / 8 waves = all 128 units; B-operand register-resident (128 VGPR/lane,
// loaded once from L2-resident Wcat). LDS = A dbuf 2x8KB only. K-loop = 1 ds_read
// + 4 MFMA per kc: no in-loop global loads, no B LDS traffic (R10's 2MB/block),
// no vmcnt drains (raw lgkm-only barrier). (512,1) -> 256-VGPR cap, 2 waves/SIMD.
__global__ __launch_bounds__(512, 1) void lstm_fused(
    const float* __restrict__ X, const float* __restrict__ Hp, const float* __restrict__ Cp,
    const __bf16* __restrict__ Wcat, const float* __restrict__ Bsum,
    float* __restrict__ out)
{
    __shared__ char abuf[2][SLAB * 512];    // 2 x 8 KB bf16 [X|h] slab, XOR-swizzled

    const int t = threadIdx.x;
    const int lane = t & 63;
    const int wv = t >> 6;                  // 0..7: unit group
    const int l16 = lane & 15;
    const int kg = lane >> 4;               // 0..3
    const long base = (long)blockIdx.x * (SLAB * NSLAB);
    const long c_off = (long)B_ROWS * H;
    const int j = wv * 16 + l16;            // this lane's unit (all 4 gates)

    // ---- B -> registers, once (Wcat is L2-resident; ~2MB total HBM across GPU) ----
    bf16x8 wreg[4][8];                      // 128 VGPR
    {
        const __bf16* wb = Wcat + (long)j * 256 + kg * 8;
#pragma unroll
        for (int g = 0; g < 4; ++g)
#pragma unroll
            for (int kc = 0; kc < 8; ++kc)
                wreg[g][kc] = *(const bf16x8*)(wb + g * (128 * 256) + kc * 32);
    }
    float bias[4];
#pragma unroll
    for (int g = 0; g < 4; ++g) bias[g] = Bsum[g * H + j];

    // staging map: thread t -> row t>>5 (0..15), 8-float group t&31 (0..15 X, 16..31 h)
    const int s_r = t >> 5;
    const int s_g8 = t & 31;

    auto stage_load = [&](float4* L, long srow) {
        const float* sp = (s_g8 < 16) ? (X + (srow + s_r) * H + s_g8 * 8)
                                      : (Hp + (srow + s_r) * H + (s_g8 - 16) * 8);
        L[0] = *(const float4*)sp;
        L[1] = *(const float4*)(sp + 4);
    };
    auto write_slab = [&](char* buf, const float4* W) {
        union { __bf16 e[8]; bf16x8 v; } u;
        float4 lo = W[0], hi = W[1];
        u.e[0] = (__bf16)lo.x; u.e[1] = (__bf16)lo.y;
        u.e[2] = (__bf16)lo.z; u.e[3] = (__bf16)lo.w;
        u.e[4] = (__bf16)hi.x; u.e[5] = (__bf16)hi.y;
        u.e[6] = (__bf16)hi.z; u.e[7] = (__bf16)hi.w;
        *(bf16x8*)(buf + s_r * 512 + ((s_g8 ^ (s_r & 7)) << 4)) = u.v;
    };
    auto load_cp = [&](float* c, long srow) {
#pragma unroll
        for (int r = 0; r < 4; ++r) c[r] = Cp[(srow + kg * 4 + r) * H + j];
    };

    float4 RA[2], RB[2];
    float cpv[4], cpn[4];

    // prologue: slab0 -> buf0; slab1 loads in flight
    stage_load(RB, base);
    load_cp(cpv, base);
    stage_load(RA, base + SLAB);
    write_slab(abuf[0], RB);                // auto vmcnt wait on RB only

#define BODY(S, W, L, BW, BC) {                                                   \
    const long srow = base + (long)(S) * SLAB;                                    \
    const long pn1 = ((S) + 1 < NSLAB) ? (S) + 1 : NSLAB - 1;                     \
    const long pn2 = ((S) + 2 < NSLAB) ? (S) + 2 : NSLAB - 1;                     \
    stage_load(L, base + pn2 * SLAB);                                             \
    load_cp(cpn, base + pn1 * SLAB);                                              \
    asm volatile("s_waitcnt lgkmcnt(0)\n\ts_barrier" ::: "memory");               \
    write_slab(abuf[BW], W);                                                      \
    const char* ac = abuf[BC];                                                    \
    f32x4 acc[4] = {};                                                            \
    _Pragma("unroll")                                                             \
    for (int kc = 0; kc < 8; ++kc) {                                              \
        int slot = ((kc * 4 + kg) ^ (l16 & 7)) << 4;                              \
        bf16x8 av = *(const bf16x8*)(ac + l16 * 512 + slot);                      \
        _Pragma("unroll")                                                         \
        for (int g = 0; g < 4; ++g)                                               \
            acc[g] = __builtin_amdgcn_mfma_f32_16x16x32_bf16(av, wreg[g][kc], acc[g], 0, 0, 0); \
    }                                                                             \
    _Pragma("unroll")                                                             \
    for (int r = 0; r < 4; ++r) {                                                 \
        long row = srow + kg * 4 + r;                                             \
        float fg = acc[0][r] + bias[0];                                           \
        float ig = acc[1][r] + bias[1];                                           \
        float cg = acc[2][r] + bias[2];                                           \
        float og = acc[3][r] + bias[3];                                           \
        float ft = fast_sigmoid(fg);                                              \
        float it = fast_sigmoid(ig);                                              \
        float cc = fast_tanh(cg);                                                 \
        float ot = fast_sigmoid(og);                                              \
        float ct = ft * cpv[r] + it * cc;                                         \
        float ht = ot * fast_tanh(ct);                                            \
        out[row * H + j] = ht;                                                    \
        out[c_off + row * H + j] = ct;                                            \
    }                                                                             \
    _Pragma("unroll")                                                             \
    for (int r = 0; r < 4; ++r) cpv[r] = cpn[r];                                  \
}

    for (int sp = 0; sp < NSLAB / 2; ++sp) {
        BODY(2 * sp,     RA, RB, 1, 0);     // write buf1 (slab 2sp+1), compute buf0
        BODY(2 * sp + 1, RB, RA, 0, 1);     // write buf0 (slab 2sp+2), compute buf1
    }
#undef BODY
}

extern "C" void kernel_launch(void* const* d_in, const int* in_sizes, int n_in,
                              void* d_out, int out_size, void* d_ws, size_t ws_size,
                              hipStream_t stream) {
    const float* X  = (const float*)d_in[0];
    const float* Hp = (const float*)d_in[1];
    const float* Cp = (const float*)d_in[2];
    WPtrs p;
    p.wx[0] = (const float*)d_in[3];  p.bx[0] = (const float*)d_in[4];
    p.wh[0] = (const float*)d_in[5];  p.bh[0] = (const float*)d_in[6];
    p.wx[1] = (const float*)d_in[7];  p.bx[1] = (const float*)d_in[8];
    p.wh[1] = (const float*)d_in[9];  p.bh[1] = (const float*)d_in[10];
    p.wx[2] = (const float*)d_in[11]; p.bx[2] = (const float*)d_in[12];
    p.wh[2] = (const float*)d_in[13]; p.bh[2] = (const float*)d_in[14];
    p.wx[3] = (const float*)d_in[15]; p.bx[3] = (const float*)d_in[16];
    p.wh[3] = (const float*)d_in[17]; p.bh[3] = (const float*)d_in[18];

    __bf16* wcat = (__bf16*)d_ws;
    float*  bsum = (float*)((char*)d_ws + 512 * 256 * 2);

    prep_weights<<<512, 256, 0, stream>>>(p, wcat, bsum);
    lstm_fused<<<NBLK, 512, 0, stream>>>(X, Hp, Cp, wcat, bsum, (float*)d_out);
}